// Round 6
// baseline (475.280 us; speedup 1.0000x reference)
//
#include <hip/hip_runtime.h>
#include <math.h>

// ---------------------------------------------------------------------------
// HybridBinaryClassifier360: conv1(3->6,5x5,s2,p1)+relu+maxpool2s1 ->
// conv2(6->15,3x3,s2,p1)+relu+maxpool2s1 -> fc 55815->120->84->1 ->
// RBF kernel vs 10 supports -> sigmoid -> [p, 1-p].  B=128, fp32.
//
// R6: despill via __launch_bounds__ second arg (R5's VGPR_Count=64 with ~75+
// live floats => accumulators spilled to scratch; that was the hidden 2x on
// VALU time). conv1 upgraded to 2-pooled-rows-per-thread (3 conv rows,
// middle shared): 25% fewer FMAs, 36% fewer LDS reads per output.
// ---------------------------------------------------------------------------

#define BATCH 128

// ---------------- Kernel 1: conv1 + relu + maxpool(2,s1) -------------------
// x [128,3,250,250] -> pool1 [128,6,123,123]
// tile: 16 pooled rows x 64 pooled cols; block 128 = 8 row-groups(x2 rows) x
// 16 strips(x4 cols). Per-ci LDS slice [37][150] (133 cols used, skew
// col+col>>3) = 22.2 KB -> 7 blocks/CU. grid (2, 8, 128).
// Thread: conv rows pr..pr+2 (pr=R0+2*tg), 5 conv cols, 6 oc = 90 accs.
#define C1_ST 150
#define C1_TOT (37 * 133)   // 4921
__global__ __launch_bounds__(128, 4) void conv1_pool_kernel(
    const float* __restrict__ x, const float* __restrict__ w,
    const float* __restrict__ bias, float* __restrict__ out) {
  const int b = blockIdx.z;
  const int P0 = blockIdx.x * 64;
  const int R0 = blockIdx.y * 16;
  const int tid = threadIdx.x;
  const int tg = tid >> 4;          // row-group 0..7 (2 pooled rows each)
  const int s = tid & 15;           // strip 0..15 (4 pooled cols)

  __shared__ float lds[37 * C1_ST];

  // acc{d}[dc][oc]: conv rows pr+d, d=0..2
  float acc0[5][6], acc1[5][6], acc2[5][6];
#pragma unroll
  for (int oc = 0; oc < 6; oc++) {
    float bv = bias[oc];
#pragma unroll
    for (int dc = 0; dc < 5; dc++) {
      acc0[dc][oc] = bv; acc1[dc][oc] = bv; acc2[dc][oc] = bv;
    }
  }

  const int ihb = 2 * R0 - 1, iwb = 2 * P0 - 1;

#pragma unroll 1
  for (int ci = 0; ci < 3; ci++) {
    __syncthreads();                 // WAR: previous ci's compute done
    const float* src = x + (size_t)(b * 3 + ci) * 62500;
#pragma unroll 1
    for (int base = tid; base < C1_TOT; base += 1024) {
      float vv[8];
#pragma unroll
      for (int k = 0; k < 8; k++) {
        int i = base + (k << 7);
        int lr = i / 133, il = i - lr * 133;
        int ih = ihb + lr, iw = iwb + il;
        bool ok = (i < C1_TOT) && ((unsigned)ih < 250u) && ((unsigned)iw < 250u);
        vv[k] = ok ? src[ih * 250 + iw] : 0.f;
      }
#pragma unroll
      for (int k = 0; k < 8; k++) {
        int i = base + (k << 7);
        if (i < C1_TOT) {
          int lr = i / 133, il = i - lr * 133;
          lds[lr * C1_ST + il + (il >> 3)] = vv[k];
        }
      }
    }
    __syncthreads();                 // RAW: staging visible

    // input rows rel to thread: 4*tg + ir, ir = 0..8
#pragma unroll 1
    for (int ir = 0; ir < 9; ir++) {
      const float* rp = &lds[(4 * tg + ir) * C1_ST + 9 * s];
      float v[13];
#pragma unroll
      for (int j = 0; j < 13; j++) v[j] = rp[j + (j >> 3)];

      if (ir <= 4) {                 // conv row pr, kh = ir
#pragma unroll
        for (int oc = 0; oc < 6; oc++) {
          const float* wr = w + ((oc * 3 + ci) * 5 + ir) * 5;
          float w0 = wr[0], w1 = wr[1], w2 = wr[2], w3 = wr[3], w4 = wr[4];
#pragma unroll
          for (int dc = 0; dc < 5; dc++) {
            float a = acc0[dc][oc];
            a += w0 * v[2 * dc + 0];
            a += w1 * v[2 * dc + 1];
            a += w2 * v[2 * dc + 2];
            a += w3 * v[2 * dc + 3];
            a += w4 * v[2 * dc + 4];
            acc0[dc][oc] = a;
          }
        }
      }
      if (ir >= 2 && ir <= 6) {      // conv row pr+1, kh = ir-2
#pragma unroll
        for (int oc = 0; oc < 6; oc++) {
          const float* wr = w + ((oc * 3 + ci) * 5 + (ir - 2)) * 5;
          float w0 = wr[0], w1 = wr[1], w2 = wr[2], w3 = wr[3], w4 = wr[4];
#pragma unroll
          for (int dc = 0; dc < 5; dc++) {
            float a = acc1[dc][oc];
            a += w0 * v[2 * dc + 0];
            a += w1 * v[2 * dc + 1];
            a += w2 * v[2 * dc + 2];
            a += w3 * v[2 * dc + 3];
            a += w4 * v[2 * dc + 4];
            acc1[dc][oc] = a;
          }
        }
      }
      if (ir >= 4) {                 // conv row pr+2, kh = ir-4
#pragma unroll
        for (int oc = 0; oc < 6; oc++) {
          const float* wr = w + ((oc * 3 + ci) * 5 + (ir - 4)) * 5;
          float w0 = wr[0], w1 = wr[1], w2 = wr[2], w3 = wr[3], w4 = wr[4];
#pragma unroll
          for (int dc = 0; dc < 5; dc++) {
            float a = acc2[dc][oc];
            a += w0 * v[2 * dc + 0];
            a += w1 * v[2 * dc + 1];
            a += w2 * v[2 * dc + 2];
            a += w3 * v[2 * dc + 3];
            a += w4 * v[2 * dc + 4];
            acc2[dc][oc] = a;
          }
        }
      }
    }
  }

  const int pr = R0 + 2 * tg;
  if (pr < 123) {                    // pooled row pr = max(conv pr, pr+1)
#pragma unroll
    for (int oc = 0; oc < 6; oc++) {
      float* orow = out + ((size_t)(b * 6 + oc) * 123 + pr) * 123;
#pragma unroll
      for (int i = 0; i < 4; i++) {
        int c = P0 + 4 * s + i;
        if (c < 123) {
          float m = fmaxf(fmaxf(acc0[i][oc], acc0[i + 1][oc]),
                          fmaxf(acc1[i][oc], acc1[i + 1][oc]));
          orow[c] = fmaxf(m, 0.f);
        }
      }
    }
  }
  if (pr + 1 < 123) {                // pooled row pr+1 = max(conv pr+1, pr+2)
#pragma unroll
    for (int oc = 0; oc < 6; oc++) {
      float* orow = out + ((size_t)(b * 6 + oc) * 123 + pr + 1) * 123;
#pragma unroll
      for (int i = 0; i < 4; i++) {
        int c = P0 + 4 * s + i;
        if (c < 123) {
          float m = fmaxf(fmaxf(acc1[i][oc], acc1[i + 1][oc]),
                          fmaxf(acc2[i][oc], acc2[i + 1][oc]));
          orow[c] = fmaxf(m, 0.f);
        }
      }
    }
  }
}

// ---------------- Kernel 2: conv2 + relu + maxpool(2,s1) -------------------
// pool1 [128,6,123,123] -> act [128, 15*61*61] (NCHW flatten)
// tile: 16 pooled rows x 32 pooled cols; block 256 = 16 rows x 16 strips(x2).
// Per-ci LDS slice [35][84] (67 cols used, skew col+col>>2) = 11.8 KB.
// Single pass over all 15 oc (90 accs -> needs the relaxed VGPR budget).
#define C2_ST 84
#define C2_TOT (35 * 67)    // 2345
__global__ __launch_bounds__(256, 3) void conv2_pool_kernel(
    const float* __restrict__ in, const float* __restrict__ w,
    const float* __restrict__ bias, float* __restrict__ out) {
  const int b = blockIdx.z;
  const int P0 = blockIdx.x * 32;
  const int R0 = blockIdx.y * 16;
  const int tid = threadIdx.x;
  const int t = tid >> 4;           // pooled row 0..15
  const int s = tid & 15;           // strip 0..15 (2 pooled cols)

  __shared__ float lds[35 * C2_ST];

  float acc0[3][15], acc1[3][15];   // conv rows r, r+1 x 3 conv cols x 15 oc
#pragma unroll
  for (int k = 0; k < 15; k++) {
    float bv = bias[k];
#pragma unroll
    for (int dc = 0; dc < 3; dc++) { acc0[dc][k] = bv; acc1[dc][k] = bv; }
  }

  const int ihb = 2 * R0 - 1, iwb = 2 * P0 - 1;

#pragma unroll 1
  for (int ci = 0; ci < 6; ci++) {
    __syncthreads();
    const float* src = in + (size_t)(b * 6 + ci) * 15129;  // 123*123
#pragma unroll 1
    for (int base = tid; base < C2_TOT; base += 2048) {
      float vv[8];
#pragma unroll
      for (int k = 0; k < 8; k++) {
        int i = base + (k << 8);
        int lr = i / 67, il = i - lr * 67;
        int ih = ihb + lr, iw = iwb + il;
        bool ok = (i < C2_TOT) && ((unsigned)ih < 123u) && ((unsigned)iw < 123u);
        vv[k] = ok ? src[ih * 123 + iw] : 0.f;
      }
#pragma unroll
      for (int k = 0; k < 8; k++) {
        int i = base + (k << 8);
        if (i < C2_TOT) {
          int lr = i / 67, il = i - lr * 67;
          lds[lr * C2_ST + il + (il >> 2)] = vv[k];
        }
      }
    }
    __syncthreads();

#pragma unroll 1
    for (int ir = 0; ir < 5; ir++) {
      const float* rp = &lds[(2 * t + ir) * C2_ST + 5 * s];
      float v[7];
#pragma unroll
      for (int j = 0; j < 7; j++) v[j] = rp[j + (j >> 2)];

      if (ir < 3) {                  // conv row r, kh = ir
#pragma unroll
        for (int k = 0; k < 15; k++) {
          const float* wr = w + ((k * 6 + ci) * 3 + ir) * 3;
          float w0 = wr[0], w1 = wr[1], w2 = wr[2];
#pragma unroll
          for (int dc = 0; dc < 3; dc++) {
            float a = acc0[dc][k];
            a += w0 * v[2 * dc + 0];
            a += w1 * v[2 * dc + 1];
            a += w2 * v[2 * dc + 2];
            acc0[dc][k] = a;
          }
        }
      }
      if (ir >= 2) {                 // conv row r+1, kh = ir-2
#pragma unroll
        for (int k = 0; k < 15; k++) {
          const float* wr = w + ((k * 6 + ci) * 3 + (ir - 2)) * 3;
          float w0 = wr[0], w1 = wr[1], w2 = wr[2];
#pragma unroll
          for (int dc = 0; dc < 3; dc++) {
            float a = acc1[dc][k];
            a += w0 * v[2 * dc + 0];
            a += w1 * v[2 * dc + 1];
            a += w2 * v[2 * dc + 2];
            acc1[dc][k] = a;
          }
        }
      }
    }
  }

  const int r = R0 + t;
  if (r < 61) {
#pragma unroll
    for (int k = 0; k < 15; k++) {
      float* orow = out + ((size_t)(b * 15 + k) * 61 + r) * 61;
#pragma unroll
      for (int i = 0; i < 2; i++) {
        int c = P0 + 2 * s + i;
        if (c < 61) {
          float m = fmaxf(fmaxf(acc0[i][k], acc0[i + 1][k]),
                          fmaxf(acc1[i][k], acc1[i + 1][k]));
          orow[c] = fmaxf(m, 0.f);
        }
      }
    }
  }
}

// ---------------- Kernel 3: fc1 split-K GEMM partials ----------------------
// C[128,120] = act[128,55815] @ fc1_w[120,55815]^T
// 512 blocks, K-chunk 112 (14 steps of 8). 2 blocks/CU.
#define KTOT 55815
#define NPART 512
#define KCHUNK 112
__global__ __launch_bounds__(256, 4) void fc1_splitk_kernel(
    const float* __restrict__ act, const float* __restrict__ w,
    float* __restrict__ partial) {
  const int kbase = blockIdx.x * KCHUNK;
  const int tid = threadIdx.x;
  const int tx = tid % 16, ty = tid / 16;
  __shared__ float ldsA[8 * 132];
  __shared__ float ldsB[8 * 132];
  float acc[8][8];
#pragma unroll
  for (int i = 0; i < 8; i++)
#pragma unroll
    for (int j = 0; j < 8; j++) acc[i][j] = 0.f;

  for (int s8 = 0; s8 < KCHUNK / 8; s8++) {
    int kofs = kbase + s8 * 8;
    __syncthreads();
    for (int i = tid; i < 1024; i += 256) {
      int m = i >> 3, kk = i & 7;
      int k = kofs + kk;
      ldsA[kk * 132 + m] = (k < KTOT) ? act[m * KTOT + k] : 0.f;
    }
    for (int i = tid; i < 960; i += 256) {
      int n = i >> 3, kk = i & 7;
      int k = kofs + kk;
      ldsB[kk * 132 + n] = (k < KTOT) ? w[n * KTOT + k] : 0.f;
    }
    __syncthreads();
#pragma unroll
    for (int kk = 0; kk < 8; kk++) {
      float4 a0 = *(const float4*)&ldsA[kk * 132 + ty * 8];
      float4 a1 = *(const float4*)&ldsA[kk * 132 + ty * 8 + 4];
      float4 b0 = *(const float4*)&ldsB[kk * 132 + tx * 8];
      float4 b1 = *(const float4*)&ldsB[kk * 132 + tx * 8 + 4];
      float av[8] = {a0.x, a0.y, a0.z, a0.w, a1.x, a1.y, a1.z, a1.w};
      float bv[8] = {b0.x, b0.y, b0.z, b0.w, b1.x, b1.y, b1.z, b1.w};
#pragma unroll
      for (int i = 0; i < 8; i++)
#pragma unroll
        for (int j = 0; j < 8; j++) acc[i][j] += av[i] * bv[j];
    }
  }

  float* dst = partial + (size_t)blockIdx.x * 15360;
#pragma unroll
  for (int i = 0; i < 8; i++) {
    int row = ty * 8 + i;
#pragma unroll
    for (int j = 0; j < 8; j++) {
      int col = tx * 8 + j;
      if (col < 120) dst[row * 120 + col] = acc[i][j];
    }
  }
}

// ---------------- Kernel 4a/4b: two-stage reduce + bias + relu -------------
__global__ __launch_bounds__(64) void fc1_reduce1_kernel(
    const float* __restrict__ partial, float* __restrict__ partial2) {
  int idx = blockIdx.x * 64 + threadIdx.x;   // 0..15359
  int g = blockIdx.y;                        // 0..7
  const float* p = partial + (size_t)g * 64 * 15360 + idx;
  float s = 0.f;
#pragma unroll 8
  for (int q = 0; q < 64; q++) s += p[(size_t)q * 15360];
  partial2[(size_t)g * 15360 + idx] = s;
}

__global__ __launch_bounds__(64) void fc1_reduce2_kernel(
    const float* __restrict__ partial2, const float* __restrict__ bias,
    float* __restrict__ h1) {
  int idx = blockIdx.x * 64 + threadIdx.x;
  float s = 0.f;
#pragma unroll
  for (int g = 0; g < 8; g++) s += partial2[(size_t)g * 15360 + idx];
  h1[idx] = fmaxf(s + bias[idx % 120], 0.f);
}

// ---------------- Kernel 5: fc2 + fc3 + RBF + sigmoid ----------------------
__global__ __launch_bounds__(128) void head_kernel(
    const float* __restrict__ h1, const float* __restrict__ fc2_w,
    const float* __restrict__ fc2_b, const float* __restrict__ fc3_w,
    const float* __restrict__ fc3_b, const float* __restrict__ support,
    float* __restrict__ out) {
  int b = blockIdx.x, t = threadIdx.x;
  __shared__ float hrow[120];
  __shared__ float s2[84];
  if (t < 120) hrow[t] = h1[b * 120 + t];
  __syncthreads();
  if (t < 84) {
    float d = fc2_b[t];
    for (int k = 0; k < 120; k++) d += fc2_w[t * 120 + k] * hrow[k];
    s2[t] = fmaxf(d, 0.f);
  }
  __syncthreads();
  if (t == 0) {
    float h = fc3_b[0];
    for (int j = 0; j < 84; j++) h += fc3_w[j] * s2[j];
    float ks = 0.f;
    for (int j = 0; j < 10; j++) {
      float diff = h - support[j];
      ks += expf(-diff * diff);
    }
    ks *= 0.1f;
    float p = 1.f / (1.f + expf(-ks));
    out[b * 2] = p;
    out[b * 2 + 1] = 1.f - p;
  }
}

// ---------------------------------------------------------------------------
extern "C" void kernel_launch(void* const* d_in, const int* in_sizes, int n_in,
                              void* d_out, int out_size, void* d_ws, size_t ws_size,
                              hipStream_t stream) {
  const float* x   = (const float*)d_in[0];
  const float* c1w = (const float*)d_in[1];
  const float* c1b = (const float*)d_in[2];
  const float* c2w = (const float*)d_in[3];
  const float* c2b = (const float*)d_in[4];
  const float* f1w = (const float*)d_in[5];
  const float* f1b = (const float*)d_in[6];
  const float* f2w = (const float*)d_in[7];
  const float* f2b = (const float*)d_in[8];
  const float* f3w = (const float*)d_in[9];
  const float* f3b = (const float*)d_in[10];
  const float* sup = (const float*)d_in[11];
  float* out = (float*)d_out;

  char* ws = (char*)d_ws;
  // Lifetimes: pool1 [0,46.5MB) dead after conv2 -> part/part2/h1 reuse it.
  float* pool1 = (float*)ws;                     // 46,476,288 B
  float* act   = (float*)(ws + 46476288);        // 28,577,280 B (alive thru fc1)
  float* part  = (float*)ws;                     // 512*15360*4 = 31,457,280 B
  float* h1    = (float*)(ws + 33000000);        //     61,440 B
  float* part2 = (float*)(ws + 34000000);        //  8*15360*4 = 491,520 B

  conv1_pool_kernel<<<dim3(2, 8, BATCH), 128, 0, stream>>>(x, c1w, c1b, pool1);
  conv2_pool_kernel<<<dim3(2, 4, BATCH), 256, 0, stream>>>(pool1, c2w, c2b, act);
  fc1_splitk_kernel<<<NPART, 256, 0, stream>>>(act, f1w, part);
  fc1_reduce1_kernel<<<dim3(240, 8), 64, 0, stream>>>(part, part2);
  fc1_reduce2_kernel<<<240, 64, 0, stream>>>(part2, f1b, h1);
  head_kernel<<<BATCH, 128, 0, stream>>>(h1, f2w, f2b, f3w, f3b, sup, out);
}

// Round 7
// 428.816 us; speedup vs baseline: 1.1084x; 1.1084x over previous
//
#include <hip/hip_runtime.h>
#include <math.h>

// ---------------------------------------------------------------------------
// HybridBinaryClassifier360: conv1(3->6,5x5,s2,p1)+relu+maxpool2s1 ->
// conv2(6->15,3x3,s2,p1)+relu+maxpool2s1 -> fc 55815->120->84->1 ->
// RBF kernel vs 10 supports -> sigmoid -> [p, 1-p].  B=128, fp32.
//
// R7: back to R5's 2-conv-row structure (R6's 3-row variant spilled at the
// stuck 64-VGPR cap: WRITE_SIZE 50->141 MB). Changes vs R5:
//  - __launch_bounds__(256,2) on conv1/conv2/fc1 -> VGPR cap 256 (despill).
//  - staging rewritten as wave-per-row / lane-per-col 2D loop: no integer
//    divisions, wave-uniform row base (scalarizable), coalesced rows.
// ---------------------------------------------------------------------------

#define BATCH 128

// ---------------- Kernel 1: conv1 + relu + maxpool(2,s1) -------------------
// x [128,3,250,250] -> pool1 [128,6,123,123]
// tile: 16 pooled rows x 64 pooled cols; block 256 = 16 rows x 16 strips(x4).
// Per-ci LDS slice [37][150] (133 cols used, skew col+col>>3) = 22.2 KB.
// grid (2, 8, 128).
#define C1_ST 150
__global__ __launch_bounds__(256, 2) void conv1_pool_kernel(
    const float* __restrict__ x, const float* __restrict__ w,
    const float* __restrict__ bias, float* __restrict__ out) {
  const int b = blockIdx.z;
  const int P0 = blockIdx.x * 64;
  const int R0 = blockIdx.y * 16;
  const int tid = threadIdx.x;
  const int t = tid >> 4;           // pooled row 0..15
  const int s = tid & 15;           // strip 0..15 (4 pooled cols)
  const int lane = tid & 63, wv = tid >> 6;

  __shared__ float lds[37 * C1_ST];

  float acc0[5][6], acc1[5][6];     // conv rows r, r+1 x 5 conv cols x 6 oc
#pragma unroll
  for (int oc = 0; oc < 6; oc++) {
    float bv = bias[oc];
#pragma unroll
    for (int dc = 0; dc < 5; dc++) { acc0[dc][oc] = bv; acc1[dc][oc] = bv; }
  }

  const int ihb = 2 * R0 - 1, iwb = 2 * P0 - 1;

#pragma unroll 1
  for (int ci = 0; ci < 3; ci++) {
    __syncthreads();                 // WAR: previous ci's compute done
    const float* src = x + (size_t)(b * 3 + ci) * 62500;
    // wave-per-row staging: row base wave-uniform, lanes sweep cols
#pragma unroll 1
    for (int lr = wv; lr < 37; lr += 4) {
      int ih = ihb + lr;
      const float* srow = src + ih * 250;
      bool rok = (unsigned)ih < 250u;
      float* drow = &lds[lr * C1_ST];
#pragma unroll
      for (int q = 0; q < 3; q++) {
        int il = lane + q * 64;      // 0..191; used < 133
        int iw = iwb + il;
        bool ok = rok && (il < 133) && ((unsigned)iw < 250u);
        float v = ok ? srow[iw] : 0.f;
        if (il < 133) drow[il + (il >> 3)] = v;
      }
    }
    __syncthreads();                 // RAW: staging visible

#pragma unroll 1
    for (int ir = 0; ir < 7; ir++) {
      const float* rp = &lds[(2 * t + ir) * C1_ST + 9 * s];
      float v[13];
#pragma unroll
      for (int j = 0; j < 13; j++) v[j] = rp[j + (j >> 3)];

      if (ir < 5) {                  // conv row r, kh = ir
#pragma unroll
        for (int oc = 0; oc < 6; oc++) {
          const float* wr = w + ((oc * 3 + ci) * 5 + ir) * 5;
          float w0 = wr[0], w1 = wr[1], w2 = wr[2], w3 = wr[3], w4 = wr[4];
#pragma unroll
          for (int dc = 0; dc < 5; dc++) {
            float a = acc0[dc][oc];
            a += w0 * v[2 * dc + 0];
            a += w1 * v[2 * dc + 1];
            a += w2 * v[2 * dc + 2];
            a += w3 * v[2 * dc + 3];
            a += w4 * v[2 * dc + 4];
            acc0[dc][oc] = a;
          }
        }
      }
      if (ir >= 2) {                 // conv row r+1, kh = ir-2
#pragma unroll
        for (int oc = 0; oc < 6; oc++) {
          const float* wr = w + ((oc * 3 + ci) * 5 + (ir - 2)) * 5;
          float w0 = wr[0], w1 = wr[1], w2 = wr[2], w3 = wr[3], w4 = wr[4];
#pragma unroll
          for (int dc = 0; dc < 5; dc++) {
            float a = acc1[dc][oc];
            a += w0 * v[2 * dc + 0];
            a += w1 * v[2 * dc + 1];
            a += w2 * v[2 * dc + 2];
            a += w3 * v[2 * dc + 3];
            a += w4 * v[2 * dc + 4];
            acc1[dc][oc] = a;
          }
        }
      }
    }
  }

  const int r = R0 + t;
  if (r < 123) {
#pragma unroll
    for (int oc = 0; oc < 6; oc++) {
      float* orow = out + ((size_t)(b * 6 + oc) * 123 + r) * 123;
#pragma unroll
      for (int i = 0; i < 4; i++) {
        int c = P0 + 4 * s + i;
        if (c < 123) {
          float m = fmaxf(fmaxf(acc0[i][oc], acc0[i + 1][oc]),
                          fmaxf(acc1[i][oc], acc1[i + 1][oc]));
          orow[c] = fmaxf(m, 0.f);
        }
      }
    }
  }
}

// ---------------- Kernel 2: conv2 + relu + maxpool(2,s1) -------------------
// pool1 [128,6,123,123] -> act [128, 15*61*61] (NCHW flatten)
// tile: 16 pooled rows x 32 pooled cols; block 256 = 16 rows x 16 strips(x2).
// Per-ci LDS slice [35][84] (67 cols used, skew col+col>>2) = 11.8 KB.
// Single pass over all 15 oc. grid (2, 4, 128).
#define C2_ST 84
__global__ __launch_bounds__(256, 2) void conv2_pool_kernel(
    const float* __restrict__ in, const float* __restrict__ w,
    const float* __restrict__ bias, float* __restrict__ out) {
  const int b = blockIdx.z;
  const int P0 = blockIdx.x * 32;
  const int R0 = blockIdx.y * 16;
  const int tid = threadIdx.x;
  const int t = tid >> 4;           // pooled row 0..15
  const int s = tid & 15;           // strip 0..15 (2 pooled cols)
  const int lane = tid & 63, wv = tid >> 6;

  __shared__ float lds[35 * C2_ST];

  float acc0[3][15], acc1[3][15];   // conv rows r, r+1 x 3 conv cols x 15 oc
#pragma unroll
  for (int k = 0; k < 15; k++) {
    float bv = bias[k];
#pragma unroll
    for (int dc = 0; dc < 3; dc++) { acc0[dc][k] = bv; acc1[dc][k] = bv; }
  }

  const int ihb = 2 * R0 - 1, iwb = 2 * P0 - 1;

#pragma unroll 1
  for (int ci = 0; ci < 6; ci++) {
    __syncthreads();
    const float* src = in + (size_t)(b * 6 + ci) * 15129;  // 123*123
#pragma unroll 1
    for (int lr = wv; lr < 35; lr += 4) {
      int ih = ihb + lr;
      const float* srow = src + ih * 123;
      bool rok = (unsigned)ih < 123u;
      float* drow = &lds[lr * C2_ST];
#pragma unroll
      for (int q = 0; q < 2; q++) {
        int il = lane + q * 64;      // 0..127; used < 67
        int iw = iwb + il;
        bool ok = rok && (il < 67) && ((unsigned)iw < 123u);
        float v = ok ? srow[iw] : 0.f;
        if (il < 67) drow[il + (il >> 2)] = v;
      }
    }
    __syncthreads();

#pragma unroll 1
    for (int ir = 0; ir < 5; ir++) {
      const float* rp = &lds[(2 * t + ir) * C2_ST + 5 * s];
      float v[7];
#pragma unroll
      for (int j = 0; j < 7; j++) v[j] = rp[j + (j >> 2)];

      if (ir < 3) {                  // conv row r, kh = ir
#pragma unroll
        for (int k = 0; k < 15; k++) {
          const float* wr = w + ((k * 6 + ci) * 3 + ir) * 3;
          float w0 = wr[0], w1 = wr[1], w2 = wr[2];
#pragma unroll
          for (int dc = 0; dc < 3; dc++) {
            float a = acc0[dc][k];
            a += w0 * v[2 * dc + 0];
            a += w1 * v[2 * dc + 1];
            a += w2 * v[2 * dc + 2];
            acc0[dc][k] = a;
          }
        }
      }
      if (ir >= 2) {                 // conv row r+1, kh = ir-2
#pragma unroll
        for (int k = 0; k < 15; k++) {
          const float* wr = w + ((k * 6 + ci) * 3 + (ir - 2)) * 3;
          float w0 = wr[0], w1 = wr[1], w2 = wr[2];
#pragma unroll
          for (int dc = 0; dc < 3; dc++) {
            float a = acc1[dc][k];
            a += w0 * v[2 * dc + 0];
            a += w1 * v[2 * dc + 1];
            a += w2 * v[2 * dc + 2];
            acc1[dc][k] = a;
          }
        }
      }
    }
  }

  const int r = R0 + t;
  if (r < 61) {
#pragma unroll
    for (int k = 0; k < 15; k++) {
      float* orow = out + ((size_t)(b * 15 + k) * 61 + r) * 61;
#pragma unroll
      for (int i = 0; i < 2; i++) {
        int c = P0 + 2 * s + i;
        if (c < 61) {
          float m = fmaxf(fmaxf(acc0[i][k], acc0[i + 1][k]),
                          fmaxf(acc1[i][k], acc1[i + 1][k]));
          orow[c] = fmaxf(m, 0.f);
        }
      }
    }
  }
}

// ---------------- Kernel 3: fc1 split-K GEMM partials ----------------------
// C[128,120] = act[128,55815] @ fc1_w[120,55815]^T
// 512 blocks, K-chunk 112 (14 steps of 8). acc 8x8 needs the 256-reg cap.
#define KTOT 55815
#define NPART 512
#define KCHUNK 112
__global__ __launch_bounds__(256, 2) void fc1_splitk_kernel(
    const float* __restrict__ act, const float* __restrict__ w,
    float* __restrict__ partial) {
  const int kbase = blockIdx.x * KCHUNK;
  const int tid = threadIdx.x;
  const int tx = tid % 16, ty = tid / 16;
  __shared__ float ldsA[8 * 132];
  __shared__ float ldsB[8 * 132];
  float acc[8][8];
#pragma unroll
  for (int i = 0; i < 8; i++)
#pragma unroll
    for (int j = 0; j < 8; j++) acc[i][j] = 0.f;

  for (int s8 = 0; s8 < KCHUNK / 8; s8++) {
    int kofs = kbase + s8 * 8;
    __syncthreads();
    for (int i = tid; i < 1024; i += 256) {
      int m = i >> 3, kk = i & 7;
      int k = kofs + kk;
      ldsA[kk * 132 + m] = (k < KTOT) ? act[m * KTOT + k] : 0.f;
    }
    for (int i = tid; i < 960; i += 256) {
      int n = i >> 3, kk = i & 7;
      int k = kofs + kk;
      ldsB[kk * 132 + n] = (k < KTOT) ? w[n * KTOT + k] : 0.f;
    }
    __syncthreads();
#pragma unroll
    for (int kk = 0; kk < 8; kk++) {
      float4 a0 = *(const float4*)&ldsA[kk * 132 + ty * 8];
      float4 a1 = *(const float4*)&ldsA[kk * 132 + ty * 8 + 4];
      float4 b0 = *(const float4*)&ldsB[kk * 132 + tx * 8];
      float4 b1 = *(const float4*)&ldsB[kk * 132 + tx * 8 + 4];
      float av[8] = {a0.x, a0.y, a0.z, a0.w, a1.x, a1.y, a1.z, a1.w};
      float bv[8] = {b0.x, b0.y, b0.z, b0.w, b1.x, b1.y, b1.z, b1.w};
#pragma unroll
      for (int i = 0; i < 8; i++)
#pragma unroll
        for (int j = 0; j < 8; j++) acc[i][j] += av[i] * bv[j];
    }
  }

  float* dst = partial + (size_t)blockIdx.x * 15360;
#pragma unroll
  for (int i = 0; i < 8; i++) {
    int row = ty * 8 + i;
#pragma unroll
    for (int j = 0; j < 8; j++) {
      int col = tx * 8 + j;
      if (col < 120) dst[row * 120 + col] = acc[i][j];
    }
  }
}

// ---------------- Kernel 4a/4b: two-stage reduce + bias + relu -------------
__global__ __launch_bounds__(64) void fc1_reduce1_kernel(
    const float* __restrict__ partial, float* __restrict__ partial2) {
  int idx = blockIdx.x * 64 + threadIdx.x;   // 0..15359
  int g = blockIdx.y;                        // 0..7
  const float* p = partial + (size_t)g * 64 * 15360 + idx;
  float s = 0.f;
#pragma unroll 8
  for (int q = 0; q < 64; q++) s += p[(size_t)q * 15360];
  partial2[(size_t)g * 15360 + idx] = s;
}

__global__ __launch_bounds__(64) void fc1_reduce2_kernel(
    const float* __restrict__ partial2, const float* __restrict__ bias,
    float* __restrict__ h1) {
  int idx = blockIdx.x * 64 + threadIdx.x;
  float s = 0.f;
#pragma unroll
  for (int g = 0; g < 8; g++) s += partial2[(size_t)g * 15360 + idx];
  h1[idx] = fmaxf(s + bias[idx % 120], 0.f);
}

// ---------------- Kernel 5: fc2 + fc3 + RBF + sigmoid ----------------------
__global__ __launch_bounds__(128) void head_kernel(
    const float* __restrict__ h1, const float* __restrict__ fc2_w,
    const float* __restrict__ fc2_b, const float* __restrict__ fc3_w,
    const float* __restrict__ fc3_b, const float* __restrict__ support,
    float* __restrict__ out) {
  int b = blockIdx.x, t = threadIdx.x;
  __shared__ float hrow[120];
  __shared__ float s2[84];
  if (t < 120) hrow[t] = h1[b * 120 + t];
  __syncthreads();
  if (t < 84) {
    float d = fc2_b[t];
    for (int k = 0; k < 120; k++) d += fc2_w[t * 120 + k] * hrow[k];
    s2[t] = fmaxf(d, 0.f);
  }
  __syncthreads();
  if (t == 0) {
    float h = fc3_b[0];
    for (int j = 0; j < 84; j++) h += fc3_w[j] * s2[j];
    float ks = 0.f;
    for (int j = 0; j < 10; j++) {
      float diff = h - support[j];
      ks += expf(-diff * diff);
    }
    ks *= 0.1f;
    float p = 1.f / (1.f + expf(-ks));
    out[b * 2] = p;
    out[b * 2 + 1] = 1.f - p;
  }
}

// ---------------------------------------------------------------------------
extern "C" void kernel_launch(void* const* d_in, const int* in_sizes, int n_in,
                              void* d_out, int out_size, void* d_ws, size_t ws_size,
                              hipStream_t stream) {
  const float* x   = (const float*)d_in[0];
  const float* c1w = (const float*)d_in[1];
  const float* c1b = (const float*)d_in[2];
  const float* c2w = (const float*)d_in[3];
  const float* c2b = (const float*)d_in[4];
  const float* f1w = (const float*)d_in[5];
  const float* f1b = (const float*)d_in[6];
  const float* f2w = (const float*)d_in[7];
  const float* f2b = (const float*)d_in[8];
  const float* f3w = (const float*)d_in[9];
  const float* f3b = (const float*)d_in[10];
  const float* sup = (const float*)d_in[11];
  float* out = (float*)d_out;

  char* ws = (char*)d_ws;
  // Lifetimes: pool1 [0,46.5MB) dead after conv2 -> part/part2/h1 reuse it.
  float* pool1 = (float*)ws;                     // 46,476,288 B
  float* act   = (float*)(ws + 46476288);        // 28,577,280 B (alive thru fc1)
  float* part  = (float*)ws;                     // 512*15360*4 = 31,457,280 B
  float* h1    = (float*)(ws + 33000000);        //     61,440 B
  float* part2 = (float*)(ws + 34000000);        //  8*15360*4 = 491,520 B

  conv1_pool_kernel<<<dim3(2, 8, BATCH), 256, 0, stream>>>(x, c1w, c1b, pool1);
  conv2_pool_kernel<<<dim3(2, 4, BATCH), 256, 0, stream>>>(pool1, c2w, c2b, act);
  fc1_splitk_kernel<<<NPART, 256, 0, stream>>>(act, f1w, part);
  fc1_reduce1_kernel<<<dim3(240, 8), 64, 0, stream>>>(part, part2);
  fc1_reduce2_kernel<<<240, 64, 0, stream>>>(part2, f1b, h1);
  head_kernel<<<BATCH, 128, 0, stream>>>(h1, f2w, f2b, f3w, f3b, sup, out);
}

// Round 8
// 360.720 us; speedup vs baseline: 1.3176x; 1.1888x over previous
//
#include <hip/hip_runtime.h>
#include <math.h>

// ---------------------------------------------------------------------------
// HybridBinaryClassifier360: conv1(3->6,5x5,s2,p1)+relu+maxpool2s1 ->
// conv2(6->15,3x3,s2,p1)+relu+maxpool2s1 -> fc 55815->120->84->1 ->
// RBF kernel vs 10 supports -> sigmoid -> [p, 1-p].  B=128, fp32.
//
// R8: VGPR_Count is pinned at 64 by the compiler's occupancy heuristic
// (launch_bounds attempts R6/R7 failed to move it) -> design every kernel to
// FIT 64 regs. conv1: R5's 8-deep MLP staging restored, integer div replaced
// by magic-mul (lr=(i*63073)>>23). conv2: two 8-oc groups (live 55 regs, no
// spill) with per-group re-staging. fc1: 512-thr blocks, 8x4 thread tile
// (live ~50). Vectorized epilogue stores everywhere.
// ---------------------------------------------------------------------------

#define BATCH 128

// ---------------- Kernel 1: conv1 + relu + maxpool(2,s1) -------------------
// x [128,3,250,250] -> pool1 [128,6,123,123]
// tile: 16 pooled rows x 64 pooled cols; block 256 = 16 rows x 16 strips(x4).
// Per-ci LDS slice [37][150] (133 cols used, skew col+col>>3) = 22.2 KB.
// grid (2, 8, 128).  Magic div: i/133 = (i*63073)>>23 (valid i < 83055).
#define C1_ST 150
#define C1_TOT (37 * 133)   // 4921
__global__ __launch_bounds__(256) void conv1_pool_kernel(
    const float* __restrict__ x, const float* __restrict__ w,
    const float* __restrict__ bias, float* __restrict__ out) {
  const int b = blockIdx.z;
  const int P0 = blockIdx.x * 64;
  const int R0 = blockIdx.y * 16;
  const int tid = threadIdx.x;
  const int t = tid >> 4;           // pooled row 0..15
  const int s = tid & 15;           // strip 0..15 (4 pooled cols)

  __shared__ float lds[37 * C1_ST];

  float acc0[5][6], acc1[5][6];     // conv rows r, r+1 x 5 conv cols x 6 oc
#pragma unroll
  for (int oc = 0; oc < 6; oc++) {
    float bv = bias[oc];
#pragma unroll
    for (int dc = 0; dc < 5; dc++) { acc0[dc][oc] = bv; acc1[dc][oc] = bv; }
  }

  const int ihb = 2 * R0 - 1, iwb = 2 * P0 - 1;

#pragma unroll 1
  for (int ci = 0; ci < 3; ci++) {
    __syncthreads();                 // WAR: previous ci's compute done
    const float* src = x + (size_t)(b * 3 + ci) * 62500;
#pragma unroll 1
    for (int base = tid; base < C1_TOT; base += 2048) {
      float vv[8];
      int lrv[8], ilv[8];
#pragma unroll
      for (int k = 0; k < 8; k++) {
        int i = base + (k << 8);
        int lr = (int)(((unsigned)i * 63073u) >> 23);   // i / 133
        int il = i - lr * 133;                          // i % 133
        lrv[k] = lr; ilv[k] = il;
        int ih = ihb + lr, iw = iwb + il;
        bool ok = (i < C1_TOT) && ((unsigned)ih < 250u) && ((unsigned)iw < 250u);
        vv[k] = ok ? src[ih * 250 + iw] : 0.f;
      }
#pragma unroll
      for (int k = 0; k < 8; k++) {
        int i = base + (k << 8);
        if (i < C1_TOT) lds[lrv[k] * C1_ST + ilv[k] + (ilv[k] >> 3)] = vv[k];
      }
    }
    __syncthreads();                 // RAW: staging visible

#pragma unroll 1
    for (int ir = 0; ir < 7; ir++) {
      const float* rp = &lds[(2 * t + ir) * C1_ST + 9 * s];
      float v[13];
#pragma unroll
      for (int j = 0; j < 13; j++) v[j] = rp[j + (j >> 3)];

      if (ir < 5) {                  // conv row r, kh = ir
#pragma unroll
        for (int oc = 0; oc < 6; oc++) {
          const float* wr = w + ((oc * 3 + ci) * 5 + ir) * 5;
          float w0 = wr[0], w1 = wr[1], w2 = wr[2], w3 = wr[3], w4 = wr[4];
#pragma unroll
          for (int dc = 0; dc < 5; dc++) {
            float a = acc0[dc][oc];
            a += w0 * v[2 * dc + 0];
            a += w1 * v[2 * dc + 1];
            a += w2 * v[2 * dc + 2];
            a += w3 * v[2 * dc + 3];
            a += w4 * v[2 * dc + 4];
            acc0[dc][oc] = a;
          }
        }
      }
      if (ir >= 2) {                 // conv row r+1, kh = ir-2
#pragma unroll
        for (int oc = 0; oc < 6; oc++) {
          const float* wr = w + ((oc * 3 + ci) * 5 + (ir - 2)) * 5;
          float w0 = wr[0], w1 = wr[1], w2 = wr[2], w3 = wr[3], w4 = wr[4];
#pragma unroll
          for (int dc = 0; dc < 5; dc++) {
            float a = acc1[dc][oc];
            a += w0 * v[2 * dc + 0];
            a += w1 * v[2 * dc + 1];
            a += w2 * v[2 * dc + 2];
            a += w3 * v[2 * dc + 3];
            a += w4 * v[2 * dc + 4];
            acc1[dc][oc] = a;
          }
        }
      }
    }
  }

  const int r = R0 + t;
  const int c0 = P0 + 4 * s;
  if (r < 123) {
#pragma unroll
    for (int oc = 0; oc < 6; oc++) {
      float* orow = out + ((size_t)(b * 6 + oc) * 123 + r) * 123;
      float m0 = fmaxf(fmaxf(fmaxf(acc0[0][oc], acc0[1][oc]),
                             fmaxf(acc1[0][oc], acc1[1][oc])), 0.f);
      float m1 = fmaxf(fmaxf(fmaxf(acc0[1][oc], acc0[2][oc]),
                             fmaxf(acc1[1][oc], acc1[2][oc])), 0.f);
      float m2 = fmaxf(fmaxf(fmaxf(acc0[2][oc], acc0[3][oc]),
                             fmaxf(acc1[2][oc], acc1[3][oc])), 0.f);
      float m3 = fmaxf(fmaxf(fmaxf(acc0[3][oc], acc0[4][oc]),
                             fmaxf(acc1[3][oc], acc1[4][oc])), 0.f);
      if (c0 + 3 < 123) {
        float4 st = make_float4(m0, m1, m2, m3);
        *(float4*)&orow[c0] = st;
      } else {
        if (c0 < 123) orow[c0] = m0;
        if (c0 + 1 < 123) orow[c0 + 1] = m1;
        if (c0 + 2 < 123) orow[c0 + 2] = m2;
      }
    }
  }
}

// ---------------- Kernel 2: conv2 + relu + maxpool(2,s1) -------------------
// pool1 [128,6,123,123] -> act [128, 15*61*61] (NCHW flatten)
// tile: 16 pooled rows x 32 pooled cols; block 256 = 16 rows x 16 strips(x2).
// Per-ci LDS slice [35][84] (67 cols used, skew col+col>>2) = 11.8 KB.
// Two 8-oc groups {0..7},{7..14} (oc7 dup), re-staged per group: live set
// 48 acc + 7 v = 55 regs -> no spill at the 64-VGPR cap.
// Magic div: i/67 = (i*125204)>>23 (valid i < 139000). grid (2, 4, 128).
#define C2_ST 84
#define C2_TOT (35 * 67)    // 2345
__global__ __launch_bounds__(256) void conv2_pool_kernel(
    const float* __restrict__ in, const float* __restrict__ w,
    const float* __restrict__ bias, float* __restrict__ out) {
  const int b = blockIdx.z;
  const int P0 = blockIdx.x * 32;
  const int R0 = blockIdx.y * 16;
  const int tid = threadIdx.x;
  const int t = tid >> 4;           // pooled row 0..15
  const int s = tid & 15;           // strip 0..15 (2 pooled cols)

  __shared__ float lds[35 * C2_ST];

  const int ihb = 2 * R0 - 1, iwb = 2 * P0 - 1;
  const int r = R0 + t;
  const int c0 = P0 + 2 * s;

#pragma unroll 1
  for (int ocg = 0; ocg < 2; ocg++) {
    const int oc0 = ocg * 7;        // {0..7}, {7..14}
    float acc0[3][8], acc1[3][8];   // conv rows r, r+1 x 3 conv cols x 8 oc
#pragma unroll
    for (int k = 0; k < 8; k++) {
      float bv = bias[oc0 + k];
#pragma unroll
      for (int dc = 0; dc < 3; dc++) { acc0[dc][k] = bv; acc1[dc][k] = bv; }
    }

#pragma unroll 1
    for (int ci = 0; ci < 6; ci++) {
      __syncthreads();               // WAR
      const float* src = in + (size_t)(b * 6 + ci) * 15129;  // 123*123
#pragma unroll 1
      for (int base = tid; base < C2_TOT; base += 2048) {
        float vv[8];
        int lrv[8], ilv[8];
#pragma unroll
        for (int k = 0; k < 8; k++) {
          int i = base + (k << 8);
          int lr = (int)(((unsigned)i * 125204u) >> 23);  // i / 67
          int il = i - lr * 67;                           // i % 67
          lrv[k] = lr; ilv[k] = il;
          int ih = ihb + lr, iw = iwb + il;
          bool ok = (i < C2_TOT) && ((unsigned)ih < 123u) && ((unsigned)iw < 123u);
          vv[k] = ok ? src[ih * 123 + iw] : 0.f;
        }
#pragma unroll
        for (int k = 0; k < 8; k++) {
          int i = base + (k << 8);
          if (i < C2_TOT) lds[lrv[k] * C2_ST + ilv[k] + (ilv[k] >> 2)] = vv[k];
        }
      }
      __syncthreads();               // RAW

#pragma unroll 1
      for (int ir = 0; ir < 5; ir++) {
        const float* rp = &lds[(2 * t + ir) * C2_ST + 5 * s];
        float v[7];
#pragma unroll
        for (int j = 0; j < 7; j++) v[j] = rp[j + (j >> 2)];

        if (ir < 3) {                // conv row r, kh = ir
#pragma unroll
          for (int k = 0; k < 8; k++) {
            const float* wr = w + (((oc0 + k) * 6 + ci) * 3 + ir) * 3;
            float w0 = wr[0], w1 = wr[1], w2 = wr[2];
#pragma unroll
            for (int dc = 0; dc < 3; dc++) {
              float a = acc0[dc][k];
              a += w0 * v[2 * dc + 0];
              a += w1 * v[2 * dc + 1];
              a += w2 * v[2 * dc + 2];
              acc0[dc][k] = a;
            }
          }
        }
        if (ir >= 2) {               // conv row r+1, kh = ir-2
#pragma unroll
          for (int k = 0; k < 8; k++) {
            const float* wr = w + (((oc0 + k) * 6 + ci) * 3 + (ir - 2)) * 3;
            float w0 = wr[0], w1 = wr[1], w2 = wr[2];
#pragma unroll
            for (int dc = 0; dc < 3; dc++) {
              float a = acc1[dc][k];
              a += w0 * v[2 * dc + 0];
              a += w1 * v[2 * dc + 1];
              a += w2 * v[2 * dc + 2];
              acc1[dc][k] = a;
            }
          }
        }
      }
    }

    if (r < 61) {
#pragma unroll
      for (int k = 0; k < 8; k++) {
        int oc = oc0 + k;
        float* orow = out + ((size_t)(b * 15 + oc) * 61 + r) * 61;
        float m0 = fmaxf(fmaxf(fmaxf(acc0[0][k], acc0[1][k]),
                               fmaxf(acc1[0][k], acc1[1][k])), 0.f);
        float m1 = fmaxf(fmaxf(fmaxf(acc0[1][k], acc0[2][k]),
                               fmaxf(acc1[1][k], acc1[2][k])), 0.f);
        if (c0 + 1 < 61) {
          float2 st = make_float2(m0, m1);
          *(float2*)&orow[c0] = st;
        } else if (c0 < 61) {
          orow[c0] = m0;
        }
      }
    }
  }
}

// ---------------- Kernel 3: fc1 split-K GEMM partials ----------------------
// C[128,120] = act[128,55815] @ fc1_w[120,55815]^T
// 512 blocks x 512 thr; thread tile 8Mx4N (acc 32 + frags 12 -> no spill).
// ty=tid>>5 (16 row-groups of 8), tx=tid&31 (cols tx*4; tx<30 active).
#define KTOT 55815
#define NPART 512
#define KCHUNK 112
__global__ __launch_bounds__(512) void fc1_splitk_kernel(
    const float* __restrict__ act, const float* __restrict__ w,
    float* __restrict__ partial) {
  const int kbase = blockIdx.x * KCHUNK;
  const int tid = threadIdx.x;
  const int tx = tid & 31, ty = tid >> 5;
  __shared__ float ldsA[8 * 132];
  __shared__ float ldsB[8 * 132];
  float acc[8][4];
#pragma unroll
  for (int i = 0; i < 8; i++)
#pragma unroll
    for (int j = 0; j < 4; j++) acc[i][j] = 0.f;

  for (int s8 = 0; s8 < KCHUNK / 8; s8++) {
    int kofs = kbase + s8 * 8;
    __syncthreads();
    for (int i = tid; i < 1024; i += 512) {
      int m = i >> 3, kk = i & 7;
      int k = kofs + kk;
      ldsA[kk * 132 + m] = (k < KTOT) ? act[m * KTOT + k] : 0.f;
    }
    for (int i = tid; i < 960; i += 512) {
      int n = i >> 3, kk = i & 7;
      int k = kofs + kk;
      ldsB[kk * 132 + n] = (k < KTOT) ? w[n * KTOT + k] : 0.f;
    }
    __syncthreads();
#pragma unroll
    for (int kk = 0; kk < 8; kk++) {
      float4 a0 = *(const float4*)&ldsA[kk * 132 + ty * 8];
      float4 a1 = *(const float4*)&ldsA[kk * 132 + ty * 8 + 4];
      float4 b0 = *(const float4*)&ldsB[kk * 132 + tx * 4];
      float av[8] = {a0.x, a0.y, a0.z, a0.w, a1.x, a1.y, a1.z, a1.w};
      float bv[4] = {b0.x, b0.y, b0.z, b0.w};
#pragma unroll
      for (int i = 0; i < 8; i++)
#pragma unroll
        for (int j = 0; j < 4; j++) acc[i][j] += av[i] * bv[j];
    }
  }

  if (tx < 30) {
    float* dst = partial + (size_t)blockIdx.x * 15360;
#pragma unroll
    for (int i = 0; i < 8; i++) {
      int row = ty * 8 + i;
      float4 st = make_float4(acc[i][0], acc[i][1], acc[i][2], acc[i][3]);
      *(float4*)&dst[row * 120 + tx * 4] = st;
    }
  }
}

// ---------------- Kernel 4a/4b: two-stage reduce + bias + relu -------------
__global__ __launch_bounds__(64) void fc1_reduce1_kernel(
    const float* __restrict__ partial, float* __restrict__ partial2) {
  int idx = blockIdx.x * 64 + threadIdx.x;   // 0..15359
  int g = blockIdx.y;                        // 0..7
  const float* p = partial + (size_t)g * 64 * 15360 + idx;
  float s = 0.f;
#pragma unroll 8
  for (int q = 0; q < 64; q++) s += p[(size_t)q * 15360];
  partial2[(size_t)g * 15360 + idx] = s;
}

__global__ __launch_bounds__(64) void fc1_reduce2_kernel(
    const float* __restrict__ partial2, const float* __restrict__ bias,
    float* __restrict__ h1) {
  int idx = blockIdx.x * 64 + threadIdx.x;
  float s = 0.f;
#pragma unroll
  for (int g = 0; g < 8; g++) s += partial2[(size_t)g * 15360 + idx];
  h1[idx] = fmaxf(s + bias[idx % 120], 0.f);
}

// ---------------- Kernel 5: fc2 + fc3 + RBF + sigmoid ----------------------
__global__ __launch_bounds__(128) void head_kernel(
    const float* __restrict__ h1, const float* __restrict__ fc2_w,
    const float* __restrict__ fc2_b, const float* __restrict__ fc3_w,
    const float* __restrict__ fc3_b, const float* __restrict__ support,
    float* __restrict__ out) {
  int b = blockIdx.x, t = threadIdx.x;
  __shared__ float hrow[120];
  __shared__ float s2[84];
  if (t < 120) hrow[t] = h1[b * 120 + t];
  __syncthreads();
  if (t < 84) {
    float d = fc2_b[t];
    for (int k = 0; k < 120; k++) d += fc2_w[t * 120 + k] * hrow[k];
    s2[t] = fmaxf(d, 0.f);
  }
  __syncthreads();
  if (t == 0) {
    float h = fc3_b[0];
    for (int j = 0; j < 84; j++) h += fc3_w[j] * s2[j];
    float ks = 0.f;
    for (int j = 0; j < 10; j++) {
      float diff = h - support[j];
      ks += expf(-diff * diff);
    }
    ks *= 0.1f;
    float p = 1.f / (1.f + expf(-ks));
    out[b * 2] = p;
    out[b * 2 + 1] = 1.f - p;
  }
}

// ---------------------------------------------------------------------------
extern "C" void kernel_launch(void* const* d_in, const int* in_sizes, int n_in,
                              void* d_out, int out_size, void* d_ws, size_t ws_size,
                              hipStream_t stream) {
  const float* x   = (const float*)d_in[0];
  const float* c1w = (const float*)d_in[1];
  const float* c1b = (const float*)d_in[2];
  const float* c2w = (const float*)d_in[3];
  const float* c2b = (const float*)d_in[4];
  const float* f1w = (const float*)d_in[5];
  const float* f1b = (const float*)d_in[6];
  const float* f2w = (const float*)d_in[7];
  const float* f2b = (const float*)d_in[8];
  const float* f3w = (const float*)d_in[9];
  const float* f3b = (const float*)d_in[10];
  const float* sup = (const float*)d_in[11];
  float* out = (float*)d_out;

  char* ws = (char*)d_ws;
  // Lifetimes: pool1 [0,46.5MB) dead after conv2 -> part/part2/h1 reuse it.
  float* pool1 = (float*)ws;                     // 46,476,288 B
  float* act   = (float*)(ws + 46476288);        // 28,577,280 B (alive thru fc1)
  float* part  = (float*)ws;                     // 512*15360*4 = 31,457,280 B
  float* h1    = (float*)(ws + 33000000);        //     61,440 B
  float* part2 = (float*)(ws + 34000000);        //  8*15360*4 = 491,520 B

  conv1_pool_kernel<<<dim3(2, 8, BATCH), 256, 0, stream>>>(x, c1w, c1b, pool1);
  conv2_pool_kernel<<<dim3(2, 4, BATCH), 256, 0, stream>>>(pool1, c2w, c2b, act);
  fc1_splitk_kernel<<<NPART, 512, 0, stream>>>(act, f1w, part);
  fc1_reduce1_kernel<<<dim3(240, 8), 64, 0, stream>>>(part, part2);
  fc1_reduce2_kernel<<<240, 64, 0, stream>>>(part2, f1b, h1);
  head_kernel<<<BATCH, 128, 0, stream>>>(h1, f2w, f2b, f3w, f3b, sup, out);
}

// Round 9
// 359.253 us; speedup vs baseline: 1.3230x; 1.0041x over previous
//
#include <hip/hip_runtime.h>
#include <math.h>

// ---------------------------------------------------------------------------
// HybridBinaryClassifier360: conv1(3->6,5x5,s2,p1)+relu+maxpool2s1 ->
// conv2(6->15,3x3,s2,p1)+relu+maxpool2s1 -> fc 55815->120->84->1 ->
// RBF kernel vs 10 supports -> sigmoid -> [p, 1-p].  B=128, fp32.
//
// R9: conv1 "compute-once" scheme. R8's conv1 was VALU-issue-bound
// (61% x 105us) with 2.67x conv recompute. Now thread t owns conv rows
// 2t,2t+1 (same 60-acc live set, fits the 64-VGPR pin) and produces TWO
// pooled rows; the one missing conv row (2t+2) comes from thread tid+8 via
// a 30-float LDS exchange in the dead input-slice buffer. Kernel FMA total
// halves. conv2/fc1/reduce/head unchanged from R8.
// ---------------------------------------------------------------------------

#define BATCH 128

// ---------------- Kernel 1: conv1 + relu + maxpool(2,s1) -------------------
// x [128,3,250,250] -> pool1 [128,6,123,123]
// tile: 31 pooled rows x 32 pooled cols; block 128 = 16 rowgroups(x2 conv
// rows) x 8 strips(x4 pooled cols). Per-ci LDS slice [67][82] (69 cols used,
// skew col+col>>3; stride 82 -> exact 2-way bank aliasing = free) = 22.0 KB.
// cbuf (exchange) 128x31 floats = 15.9 KB, unioned into the slice buffer.
// grid (4, 4, 128). Magic div: i/69 = (i*121575)>>23 (valid i < 125203).
#define C1_ST 82
#define C1_COLS 69
#define C1_ROWS 67
#define C1_TOT (C1_ROWS * C1_COLS)   // 4623
__global__ __launch_bounds__(128) void conv1_pool_kernel(
    const float* __restrict__ x, const float* __restrict__ w,
    const float* __restrict__ bias, float* __restrict__ out) {
  const int b = blockIdx.z;
  const int P0 = blockIdx.x * 32;    // first pooled col
  const int R0 = blockIdx.y * 31;    // first pooled row
  const int tid = threadIdx.x;
  const int t = tid >> 3;            // rowgroup 0..15 (conv rows 2t, 2t+1)
  const int s = tid & 7;             // strip 0..7 (4 pooled cols)

  __shared__ float lds[C1_ROWS * C1_ST];   // 5494 floats; cbuf reuses [0,3968)
  float* cbuf = lds;

  float acc0[5][6], acc1[5][6];      // conv rows 2t, 2t+1 x 5 conv cols x 6 oc
#pragma unroll
  for (int oc = 0; oc < 6; oc++) {
    float bv = bias[oc];
#pragma unroll
    for (int dc = 0; dc < 5; dc++) { acc0[dc][oc] = bv; acc1[dc][oc] = bv; }
  }

  const int ihb = 2 * R0 - 1, iwb = 2 * P0 - 1;

#pragma unroll 1
  for (int ci = 0; ci < 3; ci++) {
    __syncthreads();                 // WAR: previous ci's compute done
    const float* src = x + (size_t)(b * 3 + ci) * 62500;
#pragma unroll 1
    for (int base = tid; base < C1_TOT; base += 1024) {
      float vv[8];
      int lrv[8], ilv[8];
#pragma unroll
      for (int k = 0; k < 8; k++) {
        int i = base + (k << 7);
        int lr = (int)(((unsigned)i * 121575u) >> 23);  // i / 69
        int il = i - lr * 69;                           // i % 69
        lrv[k] = lr; ilv[k] = il;
        int ih = ihb + lr, iw = iwb + il;
        bool ok = (i < C1_TOT) && ((unsigned)ih < 250u) && ((unsigned)iw < 250u);
        vv[k] = ok ? src[ih * 250 + iw] : 0.f;
      }
#pragma unroll
      for (int k = 0; k < 8; k++) {
        int i = base + (k << 7);
        if (i < C1_TOT) lds[lrv[k] * C1_ST + ilv[k] + (ilv[k] >> 3)] = vv[k];
      }
    }
    __syncthreads();                 // RAW: staging visible

    // input slice rows for this thread: 4t + ir, ir = 0..6
#pragma unroll 1
    for (int ir = 0; ir < 7; ir++) {
      const float* rp = &lds[(4 * t + ir) * C1_ST + 9 * s];
      float v[13];
#pragma unroll
      for (int j = 0; j < 13; j++) v[j] = rp[j + (j >> 3)];

      if (ir < 5) {                  // conv row 2t, kh = ir
#pragma unroll
        for (int oc = 0; oc < 6; oc++) {
          const float* wr = w + ((oc * 3 + ci) * 5 + ir) * 5;
          float w0 = wr[0], w1 = wr[1], w2 = wr[2], w3 = wr[3], w4 = wr[4];
#pragma unroll
          for (int dc = 0; dc < 5; dc++) {
            float a = acc0[dc][oc];
            a += w0 * v[2 * dc + 0];
            a += w1 * v[2 * dc + 1];
            a += w2 * v[2 * dc + 2];
            a += w3 * v[2 * dc + 3];
            a += w4 * v[2 * dc + 4];
            acc0[dc][oc] = a;
          }
        }
      }
      if (ir >= 2) {                 // conv row 2t+1, kh = ir-2
#pragma unroll
        for (int oc = 0; oc < 6; oc++) {
          const float* wr = w + ((oc * 3 + ci) * 5 + (ir - 2)) * 5;
          float w0 = wr[0], w1 = wr[1], w2 = wr[2], w3 = wr[3], w4 = wr[4];
#pragma unroll
          for (int dc = 0; dc < 5; dc++) {
            float a = acc1[dc][oc];
            a += w0 * v[2 * dc + 0];
            a += w1 * v[2 * dc + 1];
            a += w2 * v[2 * dc + 2];
            a += w3 * v[2 * dc + 3];
            a += w4 * v[2 * dc + 4];
            acc1[dc][oc] = a;
          }
        }
      }
    }
  }

  // ---- exchange: publish acc0 (conv row 2t) for thread (t-1, same s) ----
  __syncthreads();                   // all compute done; input slice dead
#pragma unroll
  for (int oc = 0; oc < 6; oc++)
#pragma unroll
    for (int dc = 0; dc < 5; dc++)
      cbuf[tid * 31 + oc * 5 + dc] = acc0[dc][oc];

  // ---- pooled row p0 = R0+2t = max(conv 2t, conv 2t+1) (in-thread) ----
  const int p0 = R0 + 2 * t;
  const int c0 = P0 + 4 * s;
  if (p0 < 123) {
#pragma unroll
    for (int oc = 0; oc < 6; oc++) {
      float* orow = out + ((size_t)(b * 6 + oc) * 123 + p0) * 123;
      float m0 = fmaxf(fmaxf(fmaxf(acc0[0][oc], acc0[1][oc]),
                             fmaxf(acc1[0][oc], acc1[1][oc])), 0.f);
      float m1 = fmaxf(fmaxf(fmaxf(acc0[1][oc], acc0[2][oc]),
                             fmaxf(acc1[1][oc], acc1[2][oc])), 0.f);
      float m2 = fmaxf(fmaxf(fmaxf(acc0[2][oc], acc0[3][oc]),
                             fmaxf(acc1[2][oc], acc1[3][oc])), 0.f);
      float m3 = fmaxf(fmaxf(fmaxf(acc0[3][oc], acc0[4][oc]),
                             fmaxf(acc1[3][oc], acc1[4][oc])), 0.f);
      if (c0 + 3 < 123) {
        *(float4*)&orow[c0] = make_float4(m0, m1, m2, m3);
      } else {
        if (c0 < 123) orow[c0] = m0;
        if (c0 + 1 < 123) orow[c0 + 1] = m1;
        if (c0 + 2 < 123) orow[c0 + 2] = m2;
      }
    }
  }

  __syncthreads();                   // cbuf visible
  // ---- pooled row p0+1 = max(conv 2t+1, conv 2t+2 [neighbor]) ----
  if (t < 15 && p0 + 1 < 123) {
    const float* nb = &cbuf[(tid + 8) * 31];
#pragma unroll
    for (int oc = 0; oc < 6; oc++) {
      float n0 = nb[oc * 5 + 0], n1 = nb[oc * 5 + 1], n2 = nb[oc * 5 + 2];
      float n3 = nb[oc * 5 + 3], n4 = nb[oc * 5 + 4];
      float* orow = out + ((size_t)(b * 6 + oc) * 123 + p0 + 1) * 123;
      float m0 = fmaxf(fmaxf(fmaxf(acc1[0][oc], acc1[1][oc]), fmaxf(n0, n1)), 0.f);
      float m1 = fmaxf(fmaxf(fmaxf(acc1[1][oc], acc1[2][oc]), fmaxf(n1, n2)), 0.f);
      float m2 = fmaxf(fmaxf(fmaxf(acc1[2][oc], acc1[3][oc]), fmaxf(n2, n3)), 0.f);
      float m3 = fmaxf(fmaxf(fmaxf(acc1[3][oc], acc1[4][oc]), fmaxf(n3, n4)), 0.f);
      if (c0 + 3 < 123) {
        *(float4*)&orow[c0] = make_float4(m0, m1, m2, m3);
      } else {
        if (c0 < 123) orow[c0] = m0;
        if (c0 + 1 < 123) orow[c0 + 1] = m1;
        if (c0 + 2 < 123) orow[c0 + 2] = m2;
      }
    }
  }
}

// ---------------- Kernel 2: conv2 + relu + maxpool(2,s1) -------------------
// pool1 [128,6,123,123] -> act [128, 15*61*61] (NCHW flatten)
// (unchanged from R8)
#define C2_ST 84
#define C2_TOT (35 * 67)    // 2345
__global__ __launch_bounds__(256) void conv2_pool_kernel(
    const float* __restrict__ in, const float* __restrict__ w,
    const float* __restrict__ bias, float* __restrict__ out) {
  const int b = blockIdx.z;
  const int P0 = blockIdx.x * 32;
  const int R0 = blockIdx.y * 16;
  const int tid = threadIdx.x;
  const int t = tid >> 4;           // pooled row 0..15
  const int s = tid & 15;           // strip 0..15 (2 pooled cols)

  __shared__ float lds[35 * C2_ST];

  const int ihb = 2 * R0 - 1, iwb = 2 * P0 - 1;
  const int r = R0 + t;
  const int c0 = P0 + 2 * s;

#pragma unroll 1
  for (int ocg = 0; ocg < 2; ocg++) {
    const int oc0 = ocg * 7;        // {0..7}, {7..14}
    float acc0[3][8], acc1[3][8];
#pragma unroll
    for (int k = 0; k < 8; k++) {
      float bv = bias[oc0 + k];
#pragma unroll
      for (int dc = 0; dc < 3; dc++) { acc0[dc][k] = bv; acc1[dc][k] = bv; }
    }

#pragma unroll 1
    for (int ci = 0; ci < 6; ci++) {
      __syncthreads();               // WAR
      const float* src = in + (size_t)(b * 6 + ci) * 15129;  // 123*123
#pragma unroll 1
      for (int base = tid; base < C2_TOT; base += 2048) {
        float vv[8];
        int lrv[8], ilv[8];
#pragma unroll
        for (int k = 0; k < 8; k++) {
          int i = base + (k << 8);
          int lr = (int)(((unsigned)i * 125204u) >> 23);  // i / 67
          int il = i - lr * 67;                           // i % 67
          lrv[k] = lr; ilv[k] = il;
          int ih = ihb + lr, iw = iwb + il;
          bool ok = (i < C2_TOT) && ((unsigned)ih < 123u) && ((unsigned)iw < 123u);
          vv[k] = ok ? src[ih * 123 + iw] : 0.f;
        }
#pragma unroll
        for (int k = 0; k < 8; k++) {
          int i = base + (k << 8);
          if (i < C2_TOT) lds[lrv[k] * C2_ST + ilv[k] + (ilv[k] >> 2)] = vv[k];
        }
      }
      __syncthreads();               // RAW

#pragma unroll 1
      for (int ir = 0; ir < 5; ir++) {
        const float* rp = &lds[(2 * t + ir) * C2_ST + 5 * s];
        float v[7];
#pragma unroll
        for (int j = 0; j < 7; j++) v[j] = rp[j + (j >> 2)];

        if (ir < 3) {                // conv row r, kh = ir
#pragma unroll
          for (int k = 0; k < 8; k++) {
            const float* wr = w + (((oc0 + k) * 6 + ci) * 3 + ir) * 3;
            float w0 = wr[0], w1 = wr[1], w2 = wr[2];
#pragma unroll
            for (int dc = 0; dc < 3; dc++) {
              float a = acc0[dc][k];
              a += w0 * v[2 * dc + 0];
              a += w1 * v[2 * dc + 1];
              a += w2 * v[2 * dc + 2];
              acc0[dc][k] = a;
            }
          }
        }
        if (ir >= 2) {               // conv row r+1, kh = ir-2
#pragma unroll
          for (int k = 0; k < 8; k++) {
            const float* wr = w + (((oc0 + k) * 6 + ci) * 3 + (ir - 2)) * 3;
            float w0 = wr[0], w1 = wr[1], w2 = wr[2];
#pragma unroll
            for (int dc = 0; dc < 3; dc++) {
              float a = acc1[dc][k];
              a += w0 * v[2 * dc + 0];
              a += w1 * v[2 * dc + 1];
              a += w2 * v[2 * dc + 2];
              acc1[dc][k] = a;
            }
          }
        }
      }
    }

    if (r < 61) {
#pragma unroll
      for (int k = 0; k < 8; k++) {
        int oc = oc0 + k;
        float* orow = out + ((size_t)(b * 15 + oc) * 61 + r) * 61;
        float m0 = fmaxf(fmaxf(fmaxf(acc0[0][k], acc0[1][k]),
                               fmaxf(acc1[0][k], acc1[1][k])), 0.f);
        float m1 = fmaxf(fmaxf(fmaxf(acc0[1][k], acc0[2][k]),
                               fmaxf(acc1[1][k], acc1[2][k])), 0.f);
        if (c0 + 1 < 61) {
          *(float2*)&orow[c0] = make_float2(m0, m1);
        } else if (c0 < 61) {
          orow[c0] = m0;
        }
      }
    }
  }
}

// ---------------- Kernel 3: fc1 split-K GEMM partials ----------------------
// (unchanged from R8)
#define KTOT 55815
#define NPART 512
#define KCHUNK 112
__global__ __launch_bounds__(512) void fc1_splitk_kernel(
    const float* __restrict__ act, const float* __restrict__ w,
    float* __restrict__ partial) {
  const int kbase = blockIdx.x * KCHUNK;
  const int tid = threadIdx.x;
  const int tx = tid & 31, ty = tid >> 5;
  __shared__ float ldsA[8 * 132];
  __shared__ float ldsB[8 * 132];
  float acc[8][4];
#pragma unroll
  for (int i = 0; i < 8; i++)
#pragma unroll
    for (int j = 0; j < 4; j++) acc[i][j] = 0.f;

  for (int s8 = 0; s8 < KCHUNK / 8; s8++) {
    int kofs = kbase + s8 * 8;
    __syncthreads();
    for (int i = tid; i < 1024; i += 512) {
      int m = i >> 3, kk = i & 7;
      int k = kofs + kk;
      ldsA[kk * 132 + m] = (k < KTOT) ? act[m * KTOT + k] : 0.f;
    }
    for (int i = tid; i < 960; i += 512) {
      int n = i >> 3, kk = i & 7;
      int k = kofs + kk;
      ldsB[kk * 132 + n] = (k < KTOT) ? w[n * KTOT + k] : 0.f;
    }
    __syncthreads();
#pragma unroll
    for (int kk = 0; kk < 8; kk++) {
      float4 a0 = *(const float4*)&ldsA[kk * 132 + ty * 8];
      float4 a1 = *(const float4*)&ldsA[kk * 132 + ty * 8 + 4];
      float4 b0 = *(const float4*)&ldsB[kk * 132 + tx * 4];
      float av[8] = {a0.x, a0.y, a0.z, a0.w, a1.x, a1.y, a1.z, a1.w};
      float bv[4] = {b0.x, b0.y, b0.z, b0.w};
#pragma unroll
      for (int i = 0; i < 8; i++)
#pragma unroll
        for (int j = 0; j < 4; j++) acc[i][j] += av[i] * bv[j];
    }
  }

  if (tx < 30) {
    float* dst = partial + (size_t)blockIdx.x * 15360;
#pragma unroll
    for (int i = 0; i < 8; i++) {
      int row = ty * 8 + i;
      float4 st = make_float4(acc[i][0], acc[i][1], acc[i][2], acc[i][3]);
      *(float4*)&dst[row * 120 + tx * 4] = st;
    }
  }
}

// ---------------- Kernel 4a/4b: two-stage reduce + bias + relu -------------
__global__ __launch_bounds__(64) void fc1_reduce1_kernel(
    const float* __restrict__ partial, float* __restrict__ partial2) {
  int idx = blockIdx.x * 64 + threadIdx.x;   // 0..15359
  int g = blockIdx.y;                        // 0..7
  const float* p = partial + (size_t)g * 64 * 15360 + idx;
  float s = 0.f;
#pragma unroll 8
  for (int q = 0; q < 64; q++) s += p[(size_t)q * 15360];
  partial2[(size_t)g * 15360 + idx] = s;
}

__global__ __launch_bounds__(64) void fc1_reduce2_kernel(
    const float* __restrict__ partial2, const float* __restrict__ bias,
    float* __restrict__ h1) {
  int idx = blockIdx.x * 64 + threadIdx.x;
  float s = 0.f;
#pragma unroll
  for (int g = 0; g < 8; g++) s += partial2[(size_t)g * 15360 + idx];
  h1[idx] = fmaxf(s + bias[idx % 120], 0.f);
}

// ---------------- Kernel 5: fc2 + fc3 + RBF + sigmoid ----------------------
__global__ __launch_bounds__(128) void head_kernel(
    const float* __restrict__ h1, const float* __restrict__ fc2_w,
    const float* __restrict__ fc2_b, const float* __restrict__ fc3_w,
    const float* __restrict__ fc3_b, const float* __restrict__ support,
    float* __restrict__ out) {
  int b = blockIdx.x, t = threadIdx.x;
  __shared__ float hrow[120];
  __shared__ float s2[84];
  if (t < 120) hrow[t] = h1[b * 120 + t];
  __syncthreads();
  if (t < 84) {
    float d = fc2_b[t];
    for (int k = 0; k < 120; k++) d += fc2_w[t * 120 + k] * hrow[k];
    s2[t] = fmaxf(d, 0.f);
  }
  __syncthreads();
  if (t == 0) {
    float h = fc3_b[0];
    for (int j = 0; j < 84; j++) h += fc3_w[j] * s2[j];
    float ks = 0.f;
    for (int j = 0; j < 10; j++) {
      float diff = h - support[j];
      ks += expf(-diff * diff);
    }
    ks *= 0.1f;
    float p = 1.f / (1.f + expf(-ks));
    out[b * 2] = p;
    out[b * 2 + 1] = 1.f - p;
  }
}

// ---------------------------------------------------------------------------
extern "C" void kernel_launch(void* const* d_in, const int* in_sizes, int n_in,
                              void* d_out, int out_size, void* d_ws, size_t ws_size,
                              hipStream_t stream) {
  const float* x   = (const float*)d_in[0];
  const float* c1w = (const float*)d_in[1];
  const float* c1b = (const float*)d_in[2];
  const float* c2w = (const float*)d_in[3];
  const float* c2b = (const float*)d_in[4];
  const float* f1w = (const float*)d_in[5];
  const float* f1b = (const float*)d_in[6];
  const float* f2w = (const float*)d_in[7];
  const float* f2b = (const float*)d_in[8];
  const float* f3w = (const float*)d_in[9];
  const float* f3b = (const float*)d_in[10];
  const float* sup = (const float*)d_in[11];
  float* out = (float*)d_out;

  char* ws = (char*)d_ws;
  // Lifetimes: pool1 [0,46.5MB) dead after conv2 -> part/part2/h1 reuse it.
  float* pool1 = (float*)ws;                     // 46,476,288 B
  float* act   = (float*)(ws + 46476288);        // 28,577,280 B (alive thru fc1)
  float* part  = (float*)ws;                     // 512*15360*4 = 31,457,280 B
  float* h1    = (float*)(ws + 33000000);        //     61,440 B
  float* part2 = (float*)(ws + 34000000);        //  8*15360*4 = 491,520 B

  conv1_pool_kernel<<<dim3(4, 4, BATCH), 128, 0, stream>>>(x, c1w, c1b, pool1);
  conv2_pool_kernel<<<dim3(2, 4, BATCH), 256, 0, stream>>>(pool1, c2w, c2b, act);
  fc1_splitk_kernel<<<NPART, 512, 0, stream>>>(act, f1w, part);
  fc1_reduce1_kernel<<<dim3(240, 8), 64, 0, stream>>>(part, part2);
  fc1_reduce2_kernel<<<240, 64, 0, stream>>>(part2, f1b, h1);
  head_kernel<<<BATCH, 128, 0, stream>>>(h1, f2w, f2b, f3w, f3b, sup, out);
}